// Round 6
// baseline (180.627 us; speedup 1.0000x reference)
//
#include <hip/hip_runtime.h>

#define NVERT 6890
#define NJNT  24
#define NBETA 10
#define NPOSE 207
#define NBATCH 512
#define KPAD 224          // 207 pose + 10 shape + 1 template + 6 zero
#define MROWS 20736       // 108 * 192 >= 20670
#define NVC (NVERT * 3)   // 20670

#define NBA 18144         // buildA blocks: MROWS*224/256
#define NBW 1728          // buildW blocks: 6912*64/256
#define NJR 576           // jreg1 blocks: 72*8

typedef __attribute__((ext_vector_type(8))) short short8;
typedef __attribute__((ext_vector_type(4))) float floatx4;

__constant__ int c_par[NJNT]   = {-1,0,0,0,1,2,3,4,5,6,7,8,9,9,9,12,13,14,16,17,18,19,20,21};
__constant__ int c_depth[NJNT] = { 0,1,1,1,2,2,2,3,3,3,4,4,4,4,4,5,5,5,6,6,7,7,8,8};

static __device__ __forceinline__ unsigned short f2bf(float x) {
  union { float f; unsigned u; } v; v.f = x;
  unsigned r = (v.u + 0x7FFFu + ((v.u >> 16) & 1u)) >> 16;
  return (unsigned short)r;
}
static __device__ __forceinline__ float bf2f(unsigned short h) {
  union { unsigned u; float f; } v; v.u = (unsigned)h << 16;
  return v.f;
}

// direct global->LDS DMA, 16 B per lane; LDS dest = uniform base + lane*16
typedef __attribute__((address_space(1))) const void as1_void;
typedef __attribute__((address_space(3))) void as3_void;
static __device__ __forceinline__ void gl_lds16(const void* g, void* l) {
  __builtin_amdgcn_global_load_lds((as1_void*)g, (as3_void*)l, 16, 0, 0);
}

// ---- fused prep: buildA + buildW + jreg1 (independent work, one launch) ----
__global__ __launch_bounds__(256) void k_prep(
    const float* __restrict__ pdir, const float* __restrict__ sd,
    const float* __restrict__ vt, const float* __restrict__ wgt,
    const float* __restrict__ Jr,
    unsigned short* __restrict__ AT, unsigned short* __restrict__ W16,
    float* __restrict__ wsJP) {
  const int bx = blockIdx.x;
  const int tid = threadIdx.x;
  if (bx < NBA) {
    // ---- build augmented A (bf16, kt-tiled: AT[kt][row][32]) ----
    const int idx = bx * 256 + tid;
    const int kk = idx & 31;
    const int row = (idx >> 5) % MROWS;
    const int kt = idx / (MROWS * 32);
    const int k = kt * 32 + kk;
    float val = 0.f;
    if (row < NVC) {
      if (k < NPOSE)            val = pdir[(size_t)row * NPOSE + k];
      else if (k < NPOSE + 10)  val = sd[(size_t)row * 10 + (k - NPOSE)];
      else if (k == NPOSE + 10) val = vt[row];
    }
    AT[idx] = f2bf(val);
  } else if (bx < NBA + NBW) {
    // ---- build W hi/lo bf16: W16[v][64] = [hi j0..31 | lo j0..31] ----
    const int idx = (bx - NBA) * 256 + tid;
    const int v = idx >> 6, c = idx & 63, j = c & 31;
    const float w = (v < NVERT && j < 24) ? wgt[(size_t)v * 24 + j] : 0.f;
    const unsigned short hi = f2bf(w);
    W16[idx] = (c >> 5) ? f2bf(w - bf2f(hi)) : hi;
  } else {
    // ---- Jreg stage 1: partial sums over 8 vertex chunks ----
    const int jb = bx - (NBA + NBW);
    const int jc = jb % 72, j = jc / 3, c = jc % 3;
    const int chunk = jb / 72;
    const int v0 = chunk * 864;
    const int vend = min(NVERT, v0 + 864);
    float acc[11];
    #pragma unroll
    for (int k = 0; k < 11; ++k) acc[k] = 0.f;
    for (int v = v0 + tid; v < vend; v += 256) {
      const float w = Jr[j * NVERT + v];
      acc[0] += w * vt[v * 3 + c];
      const float* s = sd + (size_t)v * 30 + c * 10;
      #pragma unroll
      for (int k = 0; k < 10; ++k) acc[1 + k] += w * s[k];
    }
    #pragma unroll
    for (int off = 32; off > 0; off >>= 1) {
      #pragma unroll
      for (int k = 0; k < 11; ++k) acc[k] += __shfl_down(acc[k], off, 64);
    }
    __shared__ float red[4][11];
    const int lane = tid & 63, wv = tid >> 6;
    if (lane == 0) {
      #pragma unroll
      for (int k = 0; k < 11; ++k) red[wv][k] = acc[k];
    }
    __syncthreads();
    if (tid == 0) {
      #pragma unroll
      for (int k = 0; k < 11; ++k)
        wsJP[(size_t)(chunk * 72 + jc) * 11 + k] =
            red[0][k] + red[1][k] + red[2][k] + red[3][k];
    }
  }
}

// ---- chain v3: wave per batch, lane = joint, tree-level parallel ----
// Also zeroes the joints output region (used by k_jnt1's atomicAdd 2
// launches later — stream-ordered, race-free).
__global__ __launch_bounds__(256, 2) void k_chain3(
    const float* __restrict__ betas, const float* __restrict__ thetas,
    const float* __restrict__ scale, const float* __restrict__ trans,
    const float* __restrict__ wsJP,
    unsigned short* __restrict__ BT, unsigned short* __restrict__ G16,
    float* __restrict__ jzero) {
  __shared__ __align__(16) float sJ[792];
  __shared__ __align__(16) float sJJ[4][72];
  __shared__ __align__(16) float sM[4][288];
  __shared__ __align__(16) unsigned short sG[4][1024];
  __shared__ __align__(16) unsigned short sB[4][KPAD];

  const int tid = threadIdx.x;
  const int wv = tid >> 6, lane = tid & 63;
  const int b = blockIdx.x * 4 + wv;

  // zero joints accumulator region (512*72 = 36864 floats)
  for (int z = blockIdx.x * 256 + tid; z < NBATCH * 72; z += 32768)
    jzero[z] = 0.f;

  if (tid < 72) {
    #pragma unroll
    for (int k = 0; k < 11; ++k) {
      float s = 0.f;
      #pragma unroll
      for (int c8 = 0; c8 < 8; ++c8) s += wsJP[(size_t)(c8 * 72 + tid) * 11 + k];
      if (k == 0) sJ[tid] = s;
      else        sJ[72 + tid * 10 + (k - 1)] = s;
    }
  }
  #pragma unroll
  for (int r = 0; r < 4; ++r) {
    sG[wv][lane * 16 + r * 4 + 0] = 0; sG[wv][lane * 16 + r * 4 + 1] = 0;
    sG[wv][lane * 16 + r * 4 + 2] = 0; sG[wv][lane * 16 + r * 4 + 3] = 0;
  }
  __syncthreads();

  float R[9], t[3], M[12], Jx = 0.f, Jy = 0.f, Jz = 0.f;
  const int i = lane;
  if (i < NJNT) {
    #pragma unroll
    for (int c = 0; c < 3; ++c) {
      float a = sJ[i * 3 + c];
      const float* d = sJ + 72 + (i * 3 + c) * 10;
      #pragma unroll
      for (int s = 0; s < NBETA; ++s) a += d[s] * betas[b * NBETA + s];
      if (c == 0) Jx = a; else if (c == 1) Jy = a; else Jz = a;
    }
    sJJ[wv][i * 3 + 0] = Jx; sJJ[wv][i * 3 + 1] = Jy; sJJ[wv][i * 3 + 2] = Jz;
    const float rx = thetas[b * 72 + i * 3 + 0];
    const float ry = thetas[b * 72 + i * 3 + 1];
    const float rz = thetas[b * 72 + i * 3 + 2];
    const float th = sqrtf(rx * rx + ry * ry + rz * rz) + 1e-8f;
    const float inv = 1.f / th;
    const float x = rx * inv, y = ry * inv, z = rz * inv;
    const float cs = cosf(th), sn = sinf(th), omc = 1.f - cs;
    R[0] = cs + omc * x * x;     R[1] = omc * x * y - sn * z; R[2] = omc * x * z + sn * y;
    R[3] = omc * x * y + sn * z; R[4] = cs + omc * y * y;     R[5] = omc * y * z - sn * x;
    R[6] = omc * x * z - sn * y; R[7] = omc * y * z + sn * x; R[8] = cs + omc * z * z;
    if (i == 0) {
      const float sc = scale[0];
      #pragma unroll
      for (int k = 0; k < 9; ++k) R[k] *= sc;
    } else {
      #pragma unroll
      for (int k = 0; k < 9; ++k)
        sB[wv][(i - 1) * 9 + k] = f2bf(R[k] - ((k == 0 || k == 4 || k == 8) ? 1.f : 0.f));
    }
  }
  if (i == 0) {
    #pragma unroll
    for (int s = 0; s < NBETA; ++s) sB[wv][NPOSE + s] = f2bf(betas[b * NBETA + s]);
    sB[wv][NPOSE + 10] = 0x3F80;
    #pragma unroll
    for (int k = NPOSE + 11; k < KPAD; ++k) sB[wv][k] = 0;
  }
  __syncthreads();

  if (i < NJNT) {
    if (i == 0) { t[0] = Jx; t[1] = Jy; t[2] = Jz; }
    else {
      const int p = c_par[i];
      t[0] = Jx - sJJ[wv][p * 3 + 0];
      t[1] = Jy - sJJ[wv][p * 3 + 1];
      t[2] = Jz - sJJ[wv][p * 3 + 2];
    }
    if (i == 0) {
      #pragma unroll
      for (int r = 0; r < 3; ++r) {
        M[r*4+0] = R[r*3+0]; M[r*4+1] = R[r*3+1]; M[r*4+2] = R[r*3+2]; M[r*4+3] = t[r];
      }
      #pragma unroll
      for (int k = 0; k < 12; ++k) sM[wv][k] = M[k];
    }
  }
  __syncthreads();

  for (int lvl = 1; lvl <= 8; ++lvl) {
    if (i < NJNT && c_depth[i] == lvl) {
      const float* Mp = sM[wv] + c_par[i] * 12;
      #pragma unroll
      for (int r = 0; r < 3; ++r) {
        const float p0 = Mp[r*4+0], p1 = Mp[r*4+1], p2 = Mp[r*4+2], p3 = Mp[r*4+3];
        M[r*4+0] = p0*R[0] + p1*R[3] + p2*R[6];
        M[r*4+1] = p0*R[1] + p1*R[4] + p2*R[7];
        M[r*4+2] = p0*R[2] + p1*R[5] + p2*R[8];
        M[r*4+3] = p0*t[0] + p1*t[1] + p2*t[2] + p3;
      }
      #pragma unroll
      for (int k = 0; k < 12; ++k) sM[wv][i * 12 + k] = M[k];
    }
    __syncthreads();
  }

  // G: t-col -= M@J_i, fold trans; hi/lo bf16 split into MFMA-A layout
  if (i < NJNT) {
    #pragma unroll
    for (int r = 0; r < 3; ++r) {
      M[r*4+3] = M[r*4+3] - (M[r*4+0]*Jx + M[r*4+1]*Jy + M[r*4+2]*Jz)
               + trans[b * 3 + r];
    }
    #pragma unroll
    for (int e = 0; e < 12; ++e) {
      const float g = M[e];
      const unsigned short hi = f2bf(g);
      sG[wv][e * 32 + i]       = hi;
      sG[wv][512 + e * 32 + i] = f2bf(g - bf2f(hi));
    }
  }
  __syncthreads();

  // coalesced global writes (BT kt-tiled: BT[kt][b][32])
  *(uint4*)(G16 + (size_t)b * 1024 + lane * 16)     = *(uint4*)&sG[wv][lane * 16];
  *(uint4*)(G16 + (size_t)b * 1024 + lane * 16 + 8) = *(uint4*)&sG[wv][lane * 16 + 8];
  if (lane < 28)
    *(uint4*)(BT + ((size_t)(lane >> 2) * NBATCH + b) * 32 + (lane & 3) * 8) =
        *(uint4*)&sB[wv][lane * 8];
}

// ---- fused MFMA pose+shape GEMM + MFMA LBS ----
// Batch tile 32 (was 64): 1728 blocks, half the accumulators (24 AGPR),
// half the epilogue barriers (8 vs 16), 4 blocks/CU resident => 2x TLP.
// (256,4): total regs ~100 < 128 budget (acc halved; DMA staging is
// zero-reg). Tripwire: WRITE_SIZE >> 42 MB means spill -> revert to (256,3).
__global__ __launch_bounds__(256, 4) void k_skin4(
    const unsigned short* __restrict__ AT, const unsigned short* __restrict__ BT,
    const unsigned short* __restrict__ W16, const unsigned short* __restrict__ G16,
    float* __restrict__ out) {
  __shared__ __align__(16) char smem[33536];
  // GEMM dbuf: buf k at smem + k*14336 : A [192][32] (12288 B) then B [32][32]
  // epilogue aliases (after barrier): sV [192][17] f32, sG2 [256][40] u16
  float* sV           = (float*)smem;
  unsigned short* sG2 = (unsigned short*)(smem + 13056);

  const int tid = threadIdx.x;
  const int wv = tid >> 6, lane = tid & 63;
  const int q = lane >> 4, n = lane & 15;

  // XCD-bijective swizzle: 1728 = 8 XCD * 216; batch-block fastest within an
  // XCD chunk so the 16 batch-blocks of one AT slice share one L2.
  const int fb = blockIdx.x;
  const int vb = (fb & 7) * 216 + (fb >> 3);
  const int b0 = (vb & 15) * 32;
  const int by = vb >> 4;
  const int vc0 = by * 192;

  floatx4 acc[3][2];
  #pragma unroll
  for (int mt = 0; mt < 3; ++mt)
    #pragma unroll
    for (int nt = 0; nt < 2; ++nt) acc[mt][nt] = (floatx4)(0.f);

  // staging lane geometry: lane covers ldsrow = l>>2, col slot = l&3;
  // source k-chunk = (l&3) ^ ((l>>3)&3)  [inverse of the read swizzle]
  const int stoff = (lane >> 2) * 32 + (((lane & 3) ^ ((lane >> 3) & 3)) * 8);
  // read slot (shorts) for frag reads: c = q ^ ((n>>1)&3)
  const int rslot = ((lane >> 4) ^ ((lane >> 1) & 3)) * 8;

  const unsigned short* gA0 = AT + ((size_t)vc0 + 48 * wv) * 32 + stoff;
  const unsigned short* gB0 = BT + ((size_t)b0 + 16 * wv) * 32 + stoff;

  // prologue: stage kt=0 into buf0 (barrier drains DMA via implied vmcnt)
  {
    unsigned short* la = (unsigned short*)smem + 48 * wv * 32;
    gl_lds16(gA0,        la);
    gl_lds16(gA0 + 512,  la + 512);
    gl_lds16(gA0 + 1024, la + 1024);
    if (wv < 2) {
      unsigned short* lb = (unsigned short*)(smem + 12288) + 16 * wv * 32;
      gl_lds16(gB0, lb);
    }
  }
  __syncthreads();

  int cur = 0;
  for (int kt = 0; kt < 7; ++kt) {
    if (kt < 6) {   // DMA next tile into other buffer; drains at the barrier
      const int nb = (cur ^ 1) * 14336;
      unsigned short* la = (unsigned short*)(smem + nb) + 48 * wv * 32;
      const unsigned short* ga = gA0 + (size_t)(kt + 1) * MROWS * 32;
      gl_lds16(ga,        la);
      gl_lds16(ga + 512,  la + 512);
      gl_lds16(ga + 1024, la + 1024);
      if (wv < 2) {
        unsigned short* lb = (unsigned short*)(smem + nb + 12288) + 16 * wv * 32;
        gl_lds16(gB0 + (size_t)(kt + 1) * NBATCH * 32, lb);
      }
    }
    const unsigned short* sAc = (const unsigned short*)(smem + cur * 14336);
    const unsigned short* sBc = sAc + 6144;   // +12288 bytes
    short8 af[3], bfr[2];
    #pragma unroll
    for (int mt = 0; mt < 3; ++mt)
      af[mt] = *(const short8*)(sAc + (48 * wv + 16 * mt + n) * 32 + rslot);
    #pragma unroll
    for (int nt = 0; nt < 2; ++nt)
      bfr[nt] = *(const short8*)(sBc + (16 * nt + n) * 32 + rslot);
    #pragma unroll
    for (int mt = 0; mt < 3; ++mt)
      #pragma unroll
      for (int nt = 0; nt < 2; ++nt)
        acc[mt][nt] = __builtin_amdgcn_mfma_f32_16x16x32_bf16(
            af[mt], bfr[nt], acc[mt][nt], 0, 0, 0);
    __syncthreads();
    cur ^= 1;
  }

  // W fragments straight from global (slice is L2-resident; wave covers
  // full 128-B lines hi+lo).
  short8 wh[4], wl[4];
  #pragma unroll
  for (int vt = 0; vt < 4; ++vt) {
    const unsigned short* wr = W16 + (size_t)(by * 64 + vt * 16 + n) * 64;
    wh[vt] = *(const short8*)(wr + q * 8);
    wl[vt] = *(const short8*)(wr + 32 + q * 8);
  }

  for (int nt = 0; nt < 2; ++nt) {
    for (int s = 0; s < 2; ++s) {
      __syncthreads();
      if (s == 0) {
        #pragma unroll
        for (int mt = 0; mt < 3; ++mt)
          #pragma unroll
          for (int r = 0; r < 4; ++r)
            sV[(48 * wv + 16 * mt + 4 * q + r) * 17 + n] = acc[mt][nt][r];
      }
      const int bg0 = b0 + nt * 16 + s * 8;
      for (int i = tid; i < 1024; i += 256) {
        const int row = i >> 2, c4 = i & 3;
        const int t = row >> 5, rem = row & 31;
        *(uint4*)(sG2 + row * 40 + c4 * 8) =
            *(const uint4*)(G16 + (size_t)(bg0 + t) * 1024 + rem * 32 + c4 * 8);
      }
      __syncthreads();
      #pragma unroll
      for (int bb = 0; bb < 2; ++bb) {
        const int t = wv * 2 + bb;
        const int col = s * 8 + t;
        const int bg = b0 + nt * 16 + col;
        const short8 gh = *(const short8*)(sG2 + (t * 32 + n) * 40 + q * 8);
        const short8 gl = *(const short8*)(sG2 + (t * 32 + 16 + n) * 40 + q * 8);
        #pragma unroll
        for (int vt = 0; vt < 4; ++vt) {
          floatx4 a2 = (floatx4)(0.f);
          a2 = __builtin_amdgcn_mfma_f32_16x16x32_bf16(gh, wl[vt], a2, 0, 0, 0);
          a2 = __builtin_amdgcn_mfma_f32_16x16x32_bf16(gl, wh[vt], a2, 0, 0, 0);
          a2 = __builtin_amdgcn_mfma_f32_16x16x32_bf16(gh, wh[vt], a2, 0, 0, 0);
          const float X = sV[(48 * vt + 3 * n + 0) * 17 + col];
          const float Y = sV[(48 * vt + 3 * n + 1) * 17 + col];
          const float Z = sV[(48 * vt + 3 * n + 2) * 17 + col];
          const float o = a2[0] * X + a2[1] * Y + a2[2] * Z + a2[3];
          const int vc = vc0 + 48 * vt + 3 * n + q;
          if (q < 3 && vc < NVC)
            out[(size_t)bg * NVC + vc] = o;
        }
      }
    }
  }
}

// ---- joints: partial sums, 2 batches x 8 v-chunks per block, atomic
// accumulation into joints (zeroed by k_chain3 two launches earlier) ----
__global__ __launch_bounds__(256) void k_jnt1(
    const float* __restrict__ Jr, const float* __restrict__ res,
    float* __restrict__ joints) {
  const int b0 = blockIdx.x * 2;
  const int chunk = blockIdx.y;
  const int v0 = chunk * 864;
  const int vend = min(NVERT, v0 + 864);
  const int lane = threadIdx.x & 63, wv = threadIdx.x >> 6;
  float acc[36];
  #pragma unroll
  for (int k = 0; k < 36; ++k) acc[k] = 0.f;
  const float* rA = res + (size_t)b0 * NVC;
  const float* rB = res + (size_t)(b0 + 1) * NVC;
  for (int v = v0 + lane; v < vend; v += 64) {
    const float a0 = rA[v * 3 + 0], a1 = rA[v * 3 + 1], a2 = rA[v * 3 + 2];
    const float e0 = rB[v * 3 + 0], e1 = rB[v * 3 + 1], e2 = rB[v * 3 + 2];
    #pragma unroll
    for (int k = 0; k < 6; ++k) {
      const int j = wv + 4 * k;
      const float w = Jr[j * NVERT + v];
      acc[k*6+0] += w * a0; acc[k*6+1] += w * a1; acc[k*6+2] += w * a2;
      acc[k*6+3] += w * e0; acc[k*6+4] += w * e1; acc[k*6+5] += w * e2;
    }
  }
  #pragma unroll
  for (int off = 32; off > 0; off >>= 1) {
    #pragma unroll
    for (int k = 0; k < 36; ++k) acc[k] += __shfl_down(acc[k], off, 64);
  }
  if (lane == 0) {
    #pragma unroll
    for (int k = 0; k < 6; ++k) {
      const int j = wv + 4 * k;
      atomicAdd(&joints[(size_t)b0 * 72 + j * 3 + 0], acc[k*6+0]);
      atomicAdd(&joints[(size_t)b0 * 72 + j * 3 + 1], acc[k*6+1]);
      atomicAdd(&joints[(size_t)b0 * 72 + j * 3 + 2], acc[k*6+2]);
      atomicAdd(&joints[(size_t)(b0 + 1) * 72 + j * 3 + 0], acc[k*6+3]);
      atomicAdd(&joints[(size_t)(b0 + 1) * 72 + j * 3 + 1], acc[k*6+4]);
      atomicAdd(&joints[(size_t)(b0 + 1) * 72 + j * 3 + 2], acc[k*6+5]);
    }
  }
}

extern "C" void kernel_launch(void* const* d_in, const int* in_sizes, int n_in,
                              void* d_out, int out_size, void* d_ws, size_t ws_size,
                              hipStream_t stream) {
  const float* betas  = (const float*)d_in[0];
  const float* thetas = (const float*)d_in[1];
  const float* trans  = (const float*)d_in[2];
  const float* scale  = (const float*)d_in[3];
  const float* vtpl   = (const float*)d_in[4];
  const float* sd     = (const float*)d_in[5];
  const float* pdir   = (const float*)d_in[6];
  const float* Jr     = (const float*)d_in[7];
  const float* wgt    = (const float*)d_in[8];
  float* out = (float*)d_out;
  float* joints = out + (size_t)NBATCH * NVC;

  float* ws   = (float*)d_ws;
  float* wsJP = ws;                                          // 6336 floats
  unsigned short* AT  = (unsigned short*)(ws + 6336);        // 7*MROWS*32 == MROWS*224
  unsigned short* BT  = AT + (size_t)MROWS * KPAD;           // 7*512*32 == 512*224
  unsigned short* W16 = BT + (size_t)NBATCH * KPAD;          // 6912*64
  unsigned short* G16 = W16 + (size_t)6912 * 64;             // 512*1024

  k_prep<<<NBA + NBW + NJR, 256, 0, stream>>>(pdir, sd, vtpl, wgt, Jr, AT, W16, wsJP);
  k_chain3<<<NBATCH / 4, 256, 0, stream>>>(betas, thetas, scale, trans, wsJP, BT, G16, joints);
  k_skin4<<<1728, 256, 0, stream>>>(AT, BT, W16, G16, out);
  k_jnt1<<<dim3(NBATCH / 2, 8), 256, 0, stream>>>(Jr, out, joints);
}

// Round 7
// 176.892 us; speedup vs baseline: 1.0211x; 1.0211x over previous
//
#include <hip/hip_runtime.h>

#define NVERT 6890
#define NJNT  24
#define NBETA 10
#define NPOSE 207
#define NBATCH 512
#define KPAD 224          // 207 pose + 10 shape + 1 template + 6 zero
#define MROWS 20736       // 108 * 192 >= 20670
#define NVC (NVERT * 3)   // 20670

#define NBA 18144         // buildA blocks: MROWS*224/256
#define NBW 1728          // buildW blocks: 6912*64/256
#define NJR 576           // jreg1 blocks: 72*8

typedef __attribute__((ext_vector_type(8))) short short8;
typedef __attribute__((ext_vector_type(4))) float floatx4;

__constant__ int c_par[NJNT]   = {-1,0,0,0,1,2,3,4,5,6,7,8,9,9,9,12,13,14,16,17,18,19,20,21};
__constant__ int c_depth[NJNT] = { 0,1,1,1,2,2,2,3,3,3,4,4,4,4,4,5,5,5,6,6,7,7,8,8};

static __device__ __forceinline__ unsigned short f2bf(float x) {
  union { float f; unsigned u; } v; v.f = x;
  unsigned r = (v.u + 0x7FFFu + ((v.u >> 16) & 1u)) >> 16;
  return (unsigned short)r;
}
static __device__ __forceinline__ float bf2f(unsigned short h) {
  union { unsigned u; float f; } v; v.u = (unsigned)h << 16;
  return v.f;
}

// ---- fused prep: buildA + buildW + jreg1 (independent work, one launch) ----
__global__ __launch_bounds__(256) void k_prep(
    const float* __restrict__ pdir, const float* __restrict__ sd,
    const float* __restrict__ vt, const float* __restrict__ wgt,
    const float* __restrict__ Jr,
    unsigned short* __restrict__ AT, unsigned short* __restrict__ W16,
    float* __restrict__ wsJP) {
  const int bx = blockIdx.x;
  const int tid = threadIdx.x;
  if (bx < NBA) {
    // ---- build augmented A (bf16, kt-tiled: AT[kt][row][32]) ----
    const int idx = bx * 256 + tid;
    const int kk = idx & 31;
    const int row = (idx >> 5) % MROWS;
    const int kt = idx / (MROWS * 32);
    const int k = kt * 32 + kk;
    float val = 0.f;
    if (row < NVC) {
      if (k < NPOSE)            val = pdir[(size_t)row * NPOSE + k];
      else if (k < NPOSE + 10)  val = sd[(size_t)row * 10 + (k - NPOSE)];
      else if (k == NPOSE + 10) val = vt[row];
    }
    AT[idx] = f2bf(val);
  } else if (bx < NBA + NBW) {
    // ---- build W hi/lo bf16: W16[v][64] = [hi j0..31 | lo j0..31] ----
    const int idx = (bx - NBA) * 256 + tid;
    const int v = idx >> 6, c = idx & 63, j = c & 31;
    const float w = (v < NVERT && j < 24) ? wgt[(size_t)v * 24 + j] : 0.f;
    const unsigned short hi = f2bf(w);
    W16[idx] = (c >> 5) ? f2bf(w - bf2f(hi)) : hi;
  } else {
    // ---- Jreg stage 1: partial sums over 8 vertex chunks ----
    const int jb = bx - (NBA + NBW);
    const int jc = jb % 72, j = jc / 3, c = jc % 3;
    const int chunk = jb / 72;
    const int v0 = chunk * 864;
    const int vend = min(NVERT, v0 + 864);
    float acc[11];
    #pragma unroll
    for (int k = 0; k < 11; ++k) acc[k] = 0.f;
    for (int v = v0 + tid; v < vend; v += 256) {
      const float w = Jr[j * NVERT + v];
      acc[0] += w * vt[v * 3 + c];
      const float* s = sd + (size_t)v * 30 + c * 10;
      #pragma unroll
      for (int k = 0; k < 10; ++k) acc[1 + k] += w * s[k];
    }
    #pragma unroll
    for (int off = 32; off > 0; off >>= 1) {
      #pragma unroll
      for (int k = 0; k < 11; ++k) acc[k] += __shfl_down(acc[k], off, 64);
    }
    __shared__ float red[4][11];
    const int lane = tid & 63, wv = tid >> 6;
    if (lane == 0) {
      #pragma unroll
      for (int k = 0; k < 11; ++k) red[wv][k] = acc[k];
    }
    __syncthreads();
    if (tid == 0) {
      #pragma unroll
      for (int k = 0; k < 11; ++k)
        wsJP[(size_t)(chunk * 72 + jc) * 11 + k] =
            red[0][k] + red[1][k] + red[2][k] + red[3][k];
    }
  }
}

// ---- chain v3: wave per batch, lane = joint, tree-level parallel ----
// Also zeroes the joints output region (used by k_jnt1's atomicAdd 2
// launches later — stream-ordered, race-free).
__global__ __launch_bounds__(256, 2) void k_chain3(
    const float* __restrict__ betas, const float* __restrict__ thetas,
    const float* __restrict__ scale, const float* __restrict__ trans,
    const float* __restrict__ wsJP,
    unsigned short* __restrict__ BT, unsigned short* __restrict__ G16,
    float* __restrict__ jzero) {
  __shared__ __align__(16) float sJ[792];
  __shared__ __align__(16) float sJJ[4][72];
  __shared__ __align__(16) float sM[4][288];
  __shared__ __align__(16) unsigned short sG[4][1024];
  __shared__ __align__(16) unsigned short sB[4][KPAD];

  const int tid = threadIdx.x;
  const int wv = tid >> 6, lane = tid & 63;
  const int b = blockIdx.x * 4 + wv;

  // zero joints accumulator region (512*72 = 36864 floats)
  for (int z = blockIdx.x * 256 + tid; z < NBATCH * 72; z += 32768)
    jzero[z] = 0.f;

  if (tid < 72) {
    #pragma unroll
    for (int k = 0; k < 11; ++k) {
      float s = 0.f;
      #pragma unroll
      for (int c8 = 0; c8 < 8; ++c8) s += wsJP[(size_t)(c8 * 72 + tid) * 11 + k];
      if (k == 0) sJ[tid] = s;
      else        sJ[72 + tid * 10 + (k - 1)] = s;
    }
  }
  #pragma unroll
  for (int r = 0; r < 4; ++r) {
    sG[wv][lane * 16 + r * 4 + 0] = 0; sG[wv][lane * 16 + r * 4 + 1] = 0;
    sG[wv][lane * 16 + r * 4 + 2] = 0; sG[wv][lane * 16 + r * 4 + 3] = 0;
  }
  __syncthreads();

  float R[9], t[3], M[12], Jx = 0.f, Jy = 0.f, Jz = 0.f;
  const int i = lane;
  if (i < NJNT) {
    #pragma unroll
    for (int c = 0; c < 3; ++c) {
      float a = sJ[i * 3 + c];
      const float* d = sJ + 72 + (i * 3 + c) * 10;
      #pragma unroll
      for (int s = 0; s < NBETA; ++s) a += d[s] * betas[b * NBETA + s];
      if (c == 0) Jx = a; else if (c == 1) Jy = a; else Jz = a;
    }
    sJJ[wv][i * 3 + 0] = Jx; sJJ[wv][i * 3 + 1] = Jy; sJJ[wv][i * 3 + 2] = Jz;
    const float rx = thetas[b * 72 + i * 3 + 0];
    const float ry = thetas[b * 72 + i * 3 + 1];
    const float rz = thetas[b * 72 + i * 3 + 2];
    const float th = sqrtf(rx * rx + ry * ry + rz * rz) + 1e-8f;
    const float inv = 1.f / th;
    const float x = rx * inv, y = ry * inv, z = rz * inv;
    const float cs = cosf(th), sn = sinf(th), omc = 1.f - cs;
    R[0] = cs + omc * x * x;     R[1] = omc * x * y - sn * z; R[2] = omc * x * z + sn * y;
    R[3] = omc * x * y + sn * z; R[4] = cs + omc * y * y;     R[5] = omc * y * z - sn * x;
    R[6] = omc * x * z - sn * y; R[7] = omc * y * z + sn * x; R[8] = cs + omc * z * z;
    if (i == 0) {
      const float sc = scale[0];
      #pragma unroll
      for (int k = 0; k < 9; ++k) R[k] *= sc;
    } else {
      #pragma unroll
      for (int k = 0; k < 9; ++k)
        sB[wv][(i - 1) * 9 + k] = f2bf(R[k] - ((k == 0 || k == 4 || k == 8) ? 1.f : 0.f));
    }
  }
  if (i == 0) {
    #pragma unroll
    for (int s = 0; s < NBETA; ++s) sB[wv][NPOSE + s] = f2bf(betas[b * NBETA + s]);
    sB[wv][NPOSE + 10] = 0x3F80;
    #pragma unroll
    for (int k = NPOSE + 11; k < KPAD; ++k) sB[wv][k] = 0;
  }
  __syncthreads();

  if (i < NJNT) {
    if (i == 0) { t[0] = Jx; t[1] = Jy; t[2] = Jz; }
    else {
      const int p = c_par[i];
      t[0] = Jx - sJJ[wv][p * 3 + 0];
      t[1] = Jy - sJJ[wv][p * 3 + 1];
      t[2] = Jz - sJJ[wv][p * 3 + 2];
    }
    if (i == 0) {
      #pragma unroll
      for (int r = 0; r < 3; ++r) {
        M[r*4+0] = R[r*3+0]; M[r*4+1] = R[r*3+1]; M[r*4+2] = R[r*3+2]; M[r*4+3] = t[r];
      }
      #pragma unroll
      for (int k = 0; k < 12; ++k) sM[wv][k] = M[k];
    }
  }
  __syncthreads();

  for (int lvl = 1; lvl <= 8; ++lvl) {
    if (i < NJNT && c_depth[i] == lvl) {
      const float* Mp = sM[wv] + c_par[i] * 12;
      #pragma unroll
      for (int r = 0; r < 3; ++r) {
        const float p0 = Mp[r*4+0], p1 = Mp[r*4+1], p2 = Mp[r*4+2], p3 = Mp[r*4+3];
        M[r*4+0] = p0*R[0] + p1*R[3] + p2*R[6];
        M[r*4+1] = p0*R[1] + p1*R[4] + p2*R[7];
        M[r*4+2] = p0*R[2] + p1*R[5] + p2*R[8];
        M[r*4+3] = p0*t[0] + p1*t[1] + p2*t[2] + p3;
      }
      #pragma unroll
      for (int k = 0; k < 12; ++k) sM[wv][i * 12 + k] = M[k];
    }
    __syncthreads();
  }

  // G: t-col -= M@J_i, fold trans; hi/lo bf16 split into MFMA-A layout
  if (i < NJNT) {
    #pragma unroll
    for (int r = 0; r < 3; ++r) {
      M[r*4+3] = M[r*4+3] - (M[r*4+0]*Jx + M[r*4+1]*Jy + M[r*4+2]*Jz)
               + trans[b * 3 + r];
    }
    #pragma unroll
    for (int e = 0; e < 12; ++e) {
      const float g = M[e];
      const unsigned short hi = f2bf(g);
      sG[wv][e * 32 + i]       = hi;
      sG[wv][512 + e * 32 + i] = f2bf(g - bf2f(hi));
    }
  }
  __syncthreads();

  // coalesced global writes (BT kt-tiled: BT[kt][b][32])
  *(uint4*)(G16 + (size_t)b * 1024 + lane * 16)     = *(uint4*)&sG[wv][lane * 16];
  *(uint4*)(G16 + (size_t)b * 1024 + lane * 16 + 8) = *(uint4*)&sG[wv][lane * 16 + 8];
  if (lane < 28)
    *(uint4*)(BT + ((size_t)(lane >> 2) * NBATCH + b) * 32 + (lane & 3) * 8) =
        *(uint4*)&sB[wv][lane * 8];
}

// ---- fused MFMA pose+shape GEMM + MFMA LBS. 1D grid 864, XCD-swizzled ----
// R2/R3 proven config: batch-64 tile, (256,3), padded [row][40] LDS,
// transient reg-staged loads. (Batch-32 split regressed in R6: doubles
// per-block fixed costs; register prefetch spilled in R1/R4; DMA dbuf
// neutral in R5 — barrier drains vmcnt.)
__global__ __launch_bounds__(256, 3) void k_skin4(
    const unsigned short* __restrict__ AT, const unsigned short* __restrict__ BT,
    const unsigned short* __restrict__ W16, const unsigned short* __restrict__ G16,
    float* __restrict__ out) {
  __shared__ __align__(16) char smem[33536];
  unsigned short* sAs = (unsigned short*)smem;             // [192][40] GEMM A
  unsigned short* sBs = (unsigned short*)(smem + 15360);   // [64][40]  GEMM B
  float* sV           = (float*)smem;                      // [192][17] epi: vph
  unsigned short* sG2 = (unsigned short*)(smem + 13056);   // [256][40] epi: G hi/lo

  const int tid = threadIdx.x;
  const int wv = tid >> 6, lane = tid & 63;
  const int q = lane >> 4, n = lane & 15;

  // XCD-bijective swizzle: 864 = 8 XCD * 108; batch-block fastest within an
  // XCD chunk so all 8 batch-blocks of one AT slice share one L2.
  const int fb = blockIdx.x;
  const int vb = (fb & 7) * 108 + (fb >> 3);
  const int b0 = (vb & 7) * 64;
  const int by = vb >> 3;
  const int vc0 = by * 192;

  floatx4 acc[3][4];
  #pragma unroll
  for (int mt = 0; mt < 3; ++mt)
    #pragma unroll
    for (int nt = 0; nt < 4; ++nt) acc[mt][nt] = (floatx4)(0.f);

  const int srow = tid >> 2, sj = tid & 3;

  for (int kt = 0; kt < 7; ++kt) {
    if (kt) __syncthreads();
    // kt-tiled staging: contiguous, fully-used 128B lines per wave
    #pragma unroll
    for (int it = 0; it < 3; ++it)
      *(uint4*)(sAs + (it * 64 + srow) * 40 + sj * 8) =
          *(const uint4*)(AT + ((size_t)kt * MROWS + vc0 + it * 64 + srow) * 32 + sj * 8);
    *(uint4*)(sBs + srow * 40 + sj * 8) =
        *(const uint4*)(BT + ((size_t)kt * NBATCH + b0 + srow) * 32 + sj * 8);
    __syncthreads();
    short8 af[3], bfr[4];
    #pragma unroll
    for (int mt = 0; mt < 3; ++mt)
      af[mt] = *(const short8*)(sAs + (48 * wv + 16 * mt + n) * 40 + q * 8);
    #pragma unroll
    for (int nt = 0; nt < 4; ++nt)
      bfr[nt] = *(const short8*)(sBs + (16 * nt + n) * 40 + q * 8);
    #pragma unroll
    for (int mt = 0; mt < 3; ++mt)
      #pragma unroll
      for (int nt = 0; nt < 4; ++nt)
        acc[mt][nt] = __builtin_amdgcn_mfma_f32_16x16x32_bf16(
            af[mt], bfr[nt], acc[mt][nt], 0, 0, 0);
  }

  // W fragments straight from global (slice is L2-resident; wave covers
  // full 128-B lines hi+lo).
  short8 wh[4], wl[4];
  #pragma unroll
  for (int vt = 0; vt < 4; ++vt) {
    const unsigned short* wr = W16 + (size_t)(by * 64 + vt * 16 + n) * 64;
    wh[vt] = *(const short8*)(wr + q * 8);
    wl[vt] = *(const short8*)(wr + 32 + q * 8);
  }

  for (int nt = 0; nt < 4; ++nt) {
    for (int s = 0; s < 2; ++s) {
      __syncthreads();
      if (s == 0) {
        #pragma unroll
        for (int mt = 0; mt < 3; ++mt)
          #pragma unroll
          for (int r = 0; r < 4; ++r)
            sV[(48 * wv + 16 * mt + 4 * q + r) * 17 + n] = acc[mt][nt][r];
      }
      const int bg0 = b0 + nt * 16 + s * 8;
      for (int i = tid; i < 1024; i += 256) {
        const int row = i >> 2, c4 = i & 3;
        const int t = row >> 5, rem = row & 31;
        *(uint4*)(sG2 + row * 40 + c4 * 8) =
            *(const uint4*)(G16 + (size_t)(bg0 + t) * 1024 + rem * 32 + c4 * 8);
      }
      __syncthreads();
      #pragma unroll
      for (int bb = 0; bb < 2; ++bb) {
        const int t = wv * 2 + bb;
        const int col = s * 8 + t;
        const int bg = b0 + nt * 16 + col;
        const short8 gh = *(const short8*)(sG2 + (t * 32 + n) * 40 + q * 8);
        const short8 gl = *(const short8*)(sG2 + (t * 32 + 16 + n) * 40 + q * 8);
        #pragma unroll
        for (int vt = 0; vt < 4; ++vt) {
          floatx4 a2 = (floatx4)(0.f);
          a2 = __builtin_amdgcn_mfma_f32_16x16x32_bf16(gh, wl[vt], a2, 0, 0, 0);
          a2 = __builtin_amdgcn_mfma_f32_16x16x32_bf16(gl, wh[vt], a2, 0, 0, 0);
          a2 = __builtin_amdgcn_mfma_f32_16x16x32_bf16(gh, wh[vt], a2, 0, 0, 0);
          const float X = sV[(48 * vt + 3 * n + 0) * 17 + col];
          const float Y = sV[(48 * vt + 3 * n + 1) * 17 + col];
          const float Z = sV[(48 * vt + 3 * n + 2) * 17 + col];
          const float o = a2[0] * X + a2[1] * Y + a2[2] * Z + a2[3];
          const int vc = vc0 + 48 * vt + 3 * n + q;
          if (q < 3 && vc < NVC)
            out[(size_t)bg * NVC + vc] = o;
        }
      }
    }
  }
}

// ---- joints: partial sums, 2 batches x 8 v-chunks per block, atomic
// accumulation into joints (zeroed by k_chain3 two launches earlier) ----
__global__ __launch_bounds__(256) void k_jnt1(
    const float* __restrict__ Jr, const float* __restrict__ res,
    float* __restrict__ joints) {
  const int b0 = blockIdx.x * 2;
  const int chunk = blockIdx.y;
  const int v0 = chunk * 864;
  const int vend = min(NVERT, v0 + 864);
  const int lane = threadIdx.x & 63, wv = threadIdx.x >> 6;
  float acc[36];
  #pragma unroll
  for (int k = 0; k < 36; ++k) acc[k] = 0.f;
  const float* rA = res + (size_t)b0 * NVC;
  const float* rB = res + (size_t)(b0 + 1) * NVC;
  for (int v = v0 + lane; v < vend; v += 64) {
    const float a0 = rA[v * 3 + 0], a1 = rA[v * 3 + 1], a2 = rA[v * 3 + 2];
    const float e0 = rB[v * 3 + 0], e1 = rB[v * 3 + 1], e2 = rB[v * 3 + 2];
    #pragma unroll
    for (int k = 0; k < 6; ++k) {
      const int j = wv + 4 * k;
      const float w = Jr[j * NVERT + v];
      acc[k*6+0] += w * a0; acc[k*6+1] += w * a1; acc[k*6+2] += w * a2;
      acc[k*6+3] += w * e0; acc[k*6+4] += w * e1; acc[k*6+5] += w * e2;
    }
  }
  #pragma unroll
  for (int off = 32; off > 0; off >>= 1) {
    #pragma unroll
    for (int k = 0; k < 36; ++k) acc[k] += __shfl_down(acc[k], off, 64);
  }
  if (lane == 0) {
    #pragma unroll
    for (int k = 0; k < 6; ++k) {
      const int j = wv + 4 * k;
      atomicAdd(&joints[(size_t)b0 * 72 + j * 3 + 0], acc[k*6+0]);
      atomicAdd(&joints[(size_t)b0 * 72 + j * 3 + 1], acc[k*6+1]);
      atomicAdd(&joints[(size_t)b0 * 72 + j * 3 + 2], acc[k*6+2]);
      atomicAdd(&joints[(size_t)(b0 + 1) * 72 + j * 3 + 0], acc[k*6+3]);
      atomicAdd(&joints[(size_t)(b0 + 1) * 72 + j * 3 + 1], acc[k*6+4]);
      atomicAdd(&joints[(size_t)(b0 + 1) * 72 + j * 3 + 2], acc[k*6+5]);
    }
  }
}

extern "C" void kernel_launch(void* const* d_in, const int* in_sizes, int n_in,
                              void* d_out, int out_size, void* d_ws, size_t ws_size,
                              hipStream_t stream) {
  const float* betas  = (const float*)d_in[0];
  const float* thetas = (const float*)d_in[1];
  const float* trans  = (const float*)d_in[2];
  const float* scale  = (const float*)d_in[3];
  const float* vtpl   = (const float*)d_in[4];
  const float* sd     = (const float*)d_in[5];
  const float* pdir   = (const float*)d_in[6];
  const float* Jr     = (const float*)d_in[7];
  const float* wgt    = (const float*)d_in[8];
  float* out = (float*)d_out;
  float* joints = out + (size_t)NBATCH * NVC;

  float* ws   = (float*)d_ws;
  float* wsJP = ws;                                          // 6336 floats
  unsigned short* AT  = (unsigned short*)(ws + 6336);        // 7*MROWS*32 == MROWS*224
  unsigned short* BT  = AT + (size_t)MROWS * KPAD;           // 7*512*32 == 512*224
  unsigned short* W16 = BT + (size_t)NBATCH * KPAD;          // 6912*64
  unsigned short* G16 = W16 + (size_t)6912 * 64;             // 512*1024

  k_prep<<<NBA + NBW + NJR, 256, 0, stream>>>(pdir, sd, vtpl, wgt, Jr, AT, W16, wsJP);
  k_chain3<<<NBATCH / 4, 256, 0, stream>>>(betas, thetas, scale, trans, wsJP, BT, G16, joints);
  k_skin4<<<864, 256, 0, stream>>>(AT, BT, W16, G16, out);
  k_jnt1<<<dim3(NBATCH / 2, 8), 256, 0, stream>>>(Jr, out, joints);
}

// Round 8
// 171.341 us; speedup vs baseline: 1.0542x; 1.0324x over previous
//
#include <hip/hip_runtime.h>

#define NVERT 6890
#define NJNT  24
#define NBETA 10
#define NPOSE 207
#define NBATCH 512
#define KPAD 224          // 207 pose + 10 shape + 1 template + 6 zero
#define MROWS 20736       // 108 * 192 >= 20670
#define NVC (NVERT * 3)   // 20670

typedef __attribute__((ext_vector_type(8))) short short8;
typedef __attribute__((ext_vector_type(4))) float floatx4;

__constant__ int c_par[NJNT]   = {-1,0,0,0,1,2,3,4,5,6,7,8,9,9,9,12,13,14,16,17,18,19,20,21};
__constant__ int c_depth[NJNT] = { 0,1,1,1,2,2,2,3,3,3,4,4,4,4,4,5,5,5,6,6,7,7,8,8};

static __device__ __forceinline__ unsigned short f2bf(float x) {
  union { float f; unsigned u; } v; v.f = x;
  unsigned r = (v.u + 0x7FFFu + ((v.u >> 16) & 1u)) >> 16;
  return (unsigned short)r;
}
static __device__ __forceinline__ float bf2f(unsigned short h) {
  union { unsigned u; float f; } v; v.u = (unsigned)h << 16;
  return v.f;
}

// ---- build augmented A (bf16, kt-tiled: AT[kt][row][32]) ----
// kt-tiling makes every k_skin4 staging read a contiguous, fully-used stream.
__global__ __launch_bounds__(256) void k_buildA(
    const float* __restrict__ pdir, const float* __restrict__ sd,
    const float* __restrict__ vt, unsigned short* __restrict__ AT) {
  const int idx = blockIdx.x * 256 + threadIdx.x;   // < 7*MROWS*32
  const int kk = idx & 31;
  const int row = (idx >> 5) % MROWS;
  const int kt = idx / (MROWS * 32);
  const int k = kt * 32 + kk;
  float val = 0.f;
  if (row < NVC) {
    if (k < NPOSE)            val = pdir[(size_t)row * NPOSE + k];
    else if (k < NPOSE + 10)  val = sd[(size_t)row * 10 + (k - NPOSE)];
    else if (k == NPOSE + 10) val = vt[row];
  }
  AT[idx] = f2bf(val);
}

// ---- build W hi/lo bf16: W16[v][64] = [hi j0..31 | lo j0..31] ----
__global__ __launch_bounds__(256) void k_buildW(
    const float* __restrict__ wgt, unsigned short* __restrict__ W16) {
  const int idx = blockIdx.x * 256 + threadIdx.x;   // < 6912*64
  const int v = idx >> 6, c = idx & 63, j = c & 31, h = c >> 5;
  const float w = (v < NVERT && j < 24) ? wgt[(size_t)v * 24 + j] : 0.f;
  const unsigned short hi = f2bf(w);
  W16[idx] = h ? f2bf(w - bf2f(hi)) : hi;
}

// ---- Jreg stage 1: partial sums over 8 vertex chunks ----
__global__ __launch_bounds__(256) void k_jreg1(
    const float* __restrict__ Jr, const float* __restrict__ vt,
    const float* __restrict__ sd, float* __restrict__ wsJP) {
  const int jc = blockIdx.x, j = jc / 3, c = jc % 3;
  const int v0 = blockIdx.y * 864;
  const int vend = min(NVERT, v0 + 864);
  const int tid = threadIdx.x;
  float acc[11];
  #pragma unroll
  for (int k = 0; k < 11; ++k) acc[k] = 0.f;
  for (int v = v0 + tid; v < vend; v += 256) {
    const float w = Jr[j * NVERT + v];
    acc[0] += w * vt[v * 3 + c];
    const float* s = sd + (size_t)v * 30 + c * 10;
    #pragma unroll
    for (int k = 0; k < 10; ++k) acc[1 + k] += w * s[k];
  }
  #pragma unroll
  for (int off = 32; off > 0; off >>= 1) {
    #pragma unroll
    for (int k = 0; k < 11; ++k) acc[k] += __shfl_down(acc[k], off, 64);
  }
  __shared__ float red[4][11];
  const int lane = tid & 63, wv = tid >> 6;
  if (lane == 0) {
    #pragma unroll
    for (int k = 0; k < 11; ++k) red[wv][k] = acc[k];
  }
  __syncthreads();
  if (tid == 0) {
    #pragma unroll
    for (int k = 0; k < 11; ++k)
      wsJP[(size_t)(blockIdx.y * 72 + jc) * 11 + k] =
          red[0][k] + red[1][k] + red[2][k] + red[3][k];
  }
}

// ---- chain v3: wave per batch, lane = joint, tree-level parallel ----
// Writes BT (bf16 GEMM-B rows, kt-tiled BT[kt][b][32]) and G16 (hi/lo bf16).
__global__ __launch_bounds__(256, 2) void k_chain3(
    const float* __restrict__ betas, const float* __restrict__ thetas,
    const float* __restrict__ scale, const float* __restrict__ trans,
    const float* __restrict__ wsJP,
    unsigned short* __restrict__ BT, unsigned short* __restrict__ G16) {
  __shared__ __align__(16) float sJ[792];
  __shared__ __align__(16) float sJJ[4][72];
  __shared__ __align__(16) float sM[4][288];
  __shared__ __align__(16) unsigned short sG[4][1024];
  __shared__ __align__(16) unsigned short sB[4][KPAD];

  const int tid = threadIdx.x;
  const int wv = tid >> 6, lane = tid & 63;
  const int b = blockIdx.x * 4 + wv;

  if (tid < 72) {
    #pragma unroll
    for (int k = 0; k < 11; ++k) {
      float s = 0.f;
      #pragma unroll
      for (int c8 = 0; c8 < 8; ++c8) s += wsJP[(size_t)(c8 * 72 + tid) * 11 + k];
      if (k == 0) sJ[tid] = s;
      else        sJ[72 + tid * 10 + (k - 1)] = s;
    }
  }
  #pragma unroll
  for (int r = 0; r < 4; ++r) {
    sG[wv][lane * 16 + r * 4 + 0] = 0; sG[wv][lane * 16 + r * 4 + 1] = 0;
    sG[wv][lane * 16 + r * 4 + 2] = 0; sG[wv][lane * 16 + r * 4 + 3] = 0;
  }
  __syncthreads();

  float R[9], t[3], M[12], Jx = 0.f, Jy = 0.f, Jz = 0.f;
  const int i = lane;
  if (i < NJNT) {
    #pragma unroll
    for (int c = 0; c < 3; ++c) {
      float a = sJ[i * 3 + c];
      const float* d = sJ + 72 + (i * 3 + c) * 10;
      #pragma unroll
      for (int s = 0; s < NBETA; ++s) a += d[s] * betas[b * NBETA + s];
      if (c == 0) Jx = a; else if (c == 1) Jy = a; else Jz = a;
    }
    sJJ[wv][i * 3 + 0] = Jx; sJJ[wv][i * 3 + 1] = Jy; sJJ[wv][i * 3 + 2] = Jz;
    const float rx = thetas[b * 72 + i * 3 + 0];
    const float ry = thetas[b * 72 + i * 3 + 1];
    const float rz = thetas[b * 72 + i * 3 + 2];
    const float th = sqrtf(rx * rx + ry * ry + rz * rz) + 1e-8f;
    const float inv = 1.f / th;
    const float x = rx * inv, y = ry * inv, z = rz * inv;
    const float cs = cosf(th), sn = sinf(th), omc = 1.f - cs;
    R[0] = cs + omc * x * x;     R[1] = omc * x * y - sn * z; R[2] = omc * x * z + sn * y;
    R[3] = omc * x * y + sn * z; R[4] = cs + omc * y * y;     R[5] = omc * y * z - sn * x;
    R[6] = omc * x * z - sn * y; R[7] = omc * y * z + sn * x; R[8] = cs + omc * z * z;
    if (i == 0) {
      const float sc = scale[0];
      #pragma unroll
      for (int k = 0; k < 9; ++k) R[k] *= sc;
    } else {
      #pragma unroll
      for (int k = 0; k < 9; ++k)
        sB[wv][(i - 1) * 9 + k] = f2bf(R[k] - ((k == 0 || k == 4 || k == 8) ? 1.f : 0.f));
    }
  }
  if (i == 0) {
    #pragma unroll
    for (int s = 0; s < NBETA; ++s) sB[wv][NPOSE + s] = f2bf(betas[b * NBETA + s]);
    sB[wv][NPOSE + 10] = 0x3F80;
    #pragma unroll
    for (int k = NPOSE + 11; k < KPAD; ++k) sB[wv][k] = 0;
  }
  __syncthreads();

  if (i < NJNT) {
    if (i == 0) { t[0] = Jx; t[1] = Jy; t[2] = Jz; }
    else {
      const int p = c_par[i];
      t[0] = Jx - sJJ[wv][p * 3 + 0];
      t[1] = Jy - sJJ[wv][p * 3 + 1];
      t[2] = Jz - sJJ[wv][p * 3 + 2];
    }
    if (i == 0) {
      #pragma unroll
      for (int r = 0; r < 3; ++r) {
        M[r*4+0] = R[r*3+0]; M[r*4+1] = R[r*3+1]; M[r*4+2] = R[r*3+2]; M[r*4+3] = t[r];
      }
      #pragma unroll
      for (int k = 0; k < 12; ++k) sM[wv][k] = M[k];
    }
  }
  __syncthreads();

  for (int lvl = 1; lvl <= 8; ++lvl) {
    if (i < NJNT && c_depth[i] == lvl) {
      const float* Mp = sM[wv] + c_par[i] * 12;
      #pragma unroll
      for (int r = 0; r < 3; ++r) {
        const float p0 = Mp[r*4+0], p1 = Mp[r*4+1], p2 = Mp[r*4+2], p3 = Mp[r*4+3];
        M[r*4+0] = p0*R[0] + p1*R[3] + p2*R[6];
        M[r*4+1] = p0*R[1] + p1*R[4] + p2*R[7];
        M[r*4+2] = p0*R[2] + p1*R[5] + p2*R[8];
        M[r*4+3] = p0*t[0] + p1*t[1] + p2*t[2] + p3;
      }
      #pragma unroll
      for (int k = 0; k < 12; ++k) sM[wv][i * 12 + k] = M[k];
    }
    __syncthreads();
  }

  // G: t-col -= M@J_i, fold trans; hi/lo bf16 split into MFMA-A layout
  if (i < NJNT) {
    #pragma unroll
    for (int r = 0; r < 3; ++r) {
      M[r*4+3] = M[r*4+3] - (M[r*4+0]*Jx + M[r*4+1]*Jy + M[r*4+2]*Jz)
               + trans[b * 3 + r];
    }
    #pragma unroll
    for (int e = 0; e < 12; ++e) {
      const float g = M[e];
      const unsigned short hi = f2bf(g);
      sG[wv][e * 32 + i]       = hi;
      sG[wv][512 + e * 32 + i] = f2bf(g - bf2f(hi));
    }
  }
  __syncthreads();

  // coalesced global writes (BT kt-tiled: BT[kt][b][32])
  *(uint4*)(G16 + (size_t)b * 1024 + lane * 16)     = *(uint4*)&sG[wv][lane * 16];
  *(uint4*)(G16 + (size_t)b * 1024 + lane * 16 + 8) = *(uint4*)&sG[wv][lane * 16 + 8];
  if (lane < 28)
    *(uint4*)(BT + ((size_t)(lane >> 2) * NBATCH + b) * 32 + (lane & 3) * 8) =
        *(uint4*)&sB[wv][lane * 8];
}

// ---- fused MFMA pose+shape GEMM + MFMA LBS. 1D grid 864, XCD-swizzled ----
// launch_bounds (256,3): known-good register regime (no scratch spills).
__global__ __launch_bounds__(256, 3) void k_skin4(
    const unsigned short* __restrict__ AT, const unsigned short* __restrict__ BT,
    const unsigned short* __restrict__ W16, const unsigned short* __restrict__ G16,
    float* __restrict__ out) {
  __shared__ __align__(16) char smem[33536];
  unsigned short* sAs = (unsigned short*)smem;             // [192][40] GEMM A
  unsigned short* sBs = (unsigned short*)(smem + 15360);   // [64][40]  GEMM B
  float* sV           = (float*)smem;                      // [192][17] epi: vph
  unsigned short* sG2 = (unsigned short*)(smem + 13056);   // [256][40] epi: G hi/lo

  const int tid = threadIdx.x;
  const int wv = tid >> 6, lane = tid & 63;
  const int q = lane >> 4, n = lane & 15;

  // XCD-bijective swizzle: 864 = 8 XCD * 108; batch-block fastest within an
  // XCD chunk so all 8 batch-blocks of one AT slice share one L2.
  const int fb = blockIdx.x;
  const int vb = (fb & 7) * 108 + (fb >> 3);
  const int b0 = (vb & 7) * 64;
  const int by = vb >> 3;
  const int vc0 = by * 192;

  floatx4 acc[3][4];
  #pragma unroll
  for (int mt = 0; mt < 3; ++mt)
    #pragma unroll
    for (int nt = 0; nt < 4; ++nt) acc[mt][nt] = (floatx4)(0.f);

  const int srow = tid >> 2, sj = tid & 3;

  for (int kt = 0; kt < 7; ++kt) {
    if (kt) __syncthreads();
    // kt-tiled staging: contiguous, fully-used 128B lines per wave
    #pragma unroll
    for (int it = 0; it < 3; ++it)
      *(uint4*)(sAs + (it * 64 + srow) * 40 + sj * 8) =
          *(const uint4*)(AT + ((size_t)kt * MROWS + vc0 + it * 64 + srow) * 32 + sj * 8);
    *(uint4*)(sBs + srow * 40 + sj * 8) =
        *(const uint4*)(BT + ((size_t)kt * NBATCH + b0 + srow) * 32 + sj * 8);
    __syncthreads();
    short8 af[3], bfr[4];
    #pragma unroll
    for (int mt = 0; mt < 3; ++mt)
      af[mt] = *(const short8*)(sAs + (48 * wv + 16 * mt + n) * 40 + q * 8);
    #pragma unroll
    for (int nt = 0; nt < 4; ++nt)
      bfr[nt] = *(const short8*)(sBs + (16 * nt + n) * 40 + q * 8);
    #pragma unroll
    for (int mt = 0; mt < 3; ++mt)
      #pragma unroll
      for (int nt = 0; nt < 4; ++nt)
        acc[mt][nt] = __builtin_amdgcn_mfma_f32_16x16x32_bf16(
            af[mt], bfr[nt], acc[mt][nt], 0, 0, 0);
  }

  // W fragments straight from global (slice is L2-resident; wave covers
  // full 128-B lines hi+lo).
  short8 wh[4], wl[4];
  #pragma unroll
  for (int vt = 0; vt < 4; ++vt) {
    const unsigned short* wr = W16 + (size_t)(by * 64 + vt * 16 + n) * 64;
    wh[vt] = *(const short8*)(wr + q * 8);
    wl[vt] = *(const short8*)(wr + 32 + q * 8);
  }

  for (int nt = 0; nt < 4; ++nt) {
    for (int s = 0; s < 2; ++s) {
      __syncthreads();
      if (s == 0) {
        #pragma unroll
        for (int mt = 0; mt < 3; ++mt)
          #pragma unroll
          for (int r = 0; r < 4; ++r)
            sV[(48 * wv + 16 * mt + 4 * q + r) * 17 + n] = acc[mt][nt][r];
      }
      const int bg0 = b0 + nt * 16 + s * 8;
      for (int i = tid; i < 1024; i += 256) {
        const int row = i >> 2, c4 = i & 3;
        const int t = row >> 5, rem = row & 31;
        *(uint4*)(sG2 + row * 40 + c4 * 8) =
            *(const uint4*)(G16 + (size_t)(bg0 + t) * 1024 + rem * 32 + c4 * 8);
      }
      __syncthreads();
      #pragma unroll
      for (int bb = 0; bb < 2; ++bb) {
        const int t = wv * 2 + bb;
        const int col = s * 8 + t;
        const int bg = b0 + nt * 16 + col;
        const short8 gh = *(const short8*)(sG2 + (t * 32 + n) * 40 + q * 8);
        const short8 gl = *(const short8*)(sG2 + (t * 32 + 16 + n) * 40 + q * 8);
        #pragma unroll
        for (int vt = 0; vt < 4; ++vt) {
          floatx4 a2 = (floatx4)(0.f);
          a2 = __builtin_amdgcn_mfma_f32_16x16x32_bf16(gh, wl[vt], a2, 0, 0, 0);
          a2 = __builtin_amdgcn_mfma_f32_16x16x32_bf16(gl, wh[vt], a2, 0, 0, 0);
          a2 = __builtin_amdgcn_mfma_f32_16x16x32_bf16(gh, wh[vt], a2, 0, 0, 0);
          const float X = sV[(48 * vt + 3 * n + 0) * 17 + col];
          const float Y = sV[(48 * vt + 3 * n + 1) * 17 + col];
          const float Z = sV[(48 * vt + 3 * n + 2) * 17 + col];
          const float o = a2[0] * X + a2[1] * Y + a2[2] * Z + a2[3];
          const int vc = vc0 + 48 * vt + 3 * n + q;
          if (q < 3 && vc < NVC)
            out[(size_t)bg * NVC + vc] = o;
        }
      }
    }
  }
}

// ---- joints stage 1: partial sums, 2 batches x 8 v-chunks per block ----
__global__ __launch_bounds__(256) void k_jnt1(
    const float* __restrict__ Jr, const float* __restrict__ res,
    float* __restrict__ wsJ2) {
  const int b0 = blockIdx.x * 2;
  const int chunk = blockIdx.y;
  const int v0 = chunk * 864;
  const int vend = min(NVERT, v0 + 864);
  const int lane = threadIdx.x & 63, wv = threadIdx.x >> 6;
  float acc[36];
  #pragma unroll
  for (int k = 0; k < 36; ++k) acc[k] = 0.f;
  const float* rA = res + (size_t)b0 * NVC;
  const float* rB = res + (size_t)(b0 + 1) * NVC;
  for (int v = v0 + lane; v < vend; v += 64) {
    const float a0 = rA[v * 3 + 0], a1 = rA[v * 3 + 1], a2 = rA[v * 3 + 2];
    const float e0 = rB[v * 3 + 0], e1 = rB[v * 3 + 1], e2 = rB[v * 3 + 2];
    #pragma unroll
    for (int k = 0; k < 6; ++k) {
      const int j = wv + 4 * k;
      const float w = Jr[j * NVERT + v];
      acc[k*6+0] += w * a0; acc[k*6+1] += w * a1; acc[k*6+2] += w * a2;
      acc[k*6+3] += w * e0; acc[k*6+4] += w * e1; acc[k*6+5] += w * e2;
    }
  }
  #pragma unroll
  for (int off = 32; off > 0; off >>= 1) {
    #pragma unroll
    for (int k = 0; k < 36; ++k) acc[k] += __shfl_down(acc[k], off, 64);
  }
  if (lane == 0) {
    #pragma unroll
    for (int k = 0; k < 6; ++k) {
      const int j = wv + 4 * k;
      float* d0 = wsJ2 + ((size_t)b0 * 8 + chunk) * 72 + j * 3;
      d0[0] = acc[k*6+0]; d0[1] = acc[k*6+1]; d0[2] = acc[k*6+2];
      float* d1 = wsJ2 + ((size_t)(b0 + 1) * 8 + chunk) * 72 + j * 3;
      d1[0] = acc[k*6+3]; d1[1] = acc[k*6+4]; d1[2] = acc[k*6+5];
    }
  }
}

// ---- joints stage 2: reduce 8 chunks ----
__global__ __launch_bounds__(256) void k_jnt2(
    const float* __restrict__ wsJ2, float* __restrict__ joints) {
  const int idx = blockIdx.x * 256 + threadIdx.x;   // < 512*72 = 36864
  const int b = idx / 72, jc = idx - b * 72;
  float s = 0.f;
  #pragma unroll
  for (int c8 = 0; c8 < 8; ++c8)
    s += wsJ2[((size_t)b * 8 + c8) * 72 + jc];
  joints[idx] = s;
}

extern "C" void kernel_launch(void* const* d_in, const int* in_sizes, int n_in,
                              void* d_out, int out_size, void* d_ws, size_t ws_size,
                              hipStream_t stream) {
  const float* betas  = (const float*)d_in[0];
  const float* thetas = (const float*)d_in[1];
  const float* trans  = (const float*)d_in[2];
  const float* scale  = (const float*)d_in[3];
  const float* vtpl   = (const float*)d_in[4];
  const float* sd     = (const float*)d_in[5];
  const float* pdir   = (const float*)d_in[6];
  const float* Jr     = (const float*)d_in[7];
  const float* wgt    = (const float*)d_in[8];
  float* out = (float*)d_out;

  float* ws   = (float*)d_ws;
  float* wsJP = ws;                                          // 6336 floats
  unsigned short* AT  = (unsigned short*)(ws + 6336);        // 7*MROWS*32 == MROWS*224
  unsigned short* BT  = AT + (size_t)MROWS * KPAD;           // 7*512*32 == 512*224
  unsigned short* W16 = BT + (size_t)NBATCH * KPAD;          // 6912*64
  unsigned short* G16 = W16 + (size_t)6912 * 64;             // 512*1024
  // wsJ2 (512*8*72 floats = 1.18 MB) aliases AT: AT is dead after k_skin4,
  // and k_jnt1 runs after k_skin4 on the same stream (in-order).
  float* wsJ2 = (float*)AT;

  k_buildA<<<(MROWS * KPAD) / 256, 256, 0, stream>>>(pdir, sd, vtpl, AT);
  k_buildW<<<(6912 * 64) / 256, 256, 0, stream>>>(wgt, W16);
  k_jreg1<<<dim3(72, 8), 256, 0, stream>>>(Jr, vtpl, sd, wsJP);
  k_chain3<<<NBATCH / 4, 256, 0, stream>>>(betas, thetas, scale, trans, wsJP, BT, G16);
  k_skin4<<<864, 256, 0, stream>>>(AT, BT, W16, G16, out);
  k_jnt1<<<dim3(NBATCH / 2, 8), 256, 0, stream>>>(Jr, out, wsJ2);
  k_jnt2<<<(NBATCH * 72) / 256, 256, 0, stream>>>(wsJ2, out + (size_t)NBATCH * NVC);
}